// Round 2
// baseline (347.398 us; speedup 1.0000x reference)
//
#include <hip/hip_runtime.h>
#include <math.h>

#define IMG_H 512
#define IMG_W 512
#define N_IMG 96            // 32 * 3
#define TW 64               // tile width (output cols)
#define TH 16               // tile height (output rows)
#define HALO 5
#define KS 11
#define IN_ROWS 26          // TH + 2*HALO
#define IN_COLS 74          // TW + 2*HALO
#define IN_STRIDE 84        // padded; 84*4 = 336 B, 16B-aligned rows
#define NBLOCKS (N_IMG * (IMG_W / TW) * (IMG_H / TH))   // 24576
#define TOTAL_N 25165824.0  // 32*3*512*512

// LDS plan (aliased union, 8320 floats = 33,280 B):
//   phase A: sP[26][84] (2184 floats) | sT[26][84] (2184 floats)
//   phase B: packed h-maps H[(r*16+cg)*20 + m*4 + ci]
//            r in [0,26), cg in [0,16), m in [0,5), ci in [0,4)
// Bank analysis:
//   - H writes: float4 per map at lane stride 20 dwords -> 2 lanes/bank (free)
//   - H reads (stage 2): addr = cg*20 + ci (+ const row) over 64 lanes covers
//     all 32 banks exactly twice -> 2 lanes/bank (free)

__global__ __launch_bounds__(256, 4) void ssim_tile_kernel(
    const float* __restrict__ pred, const float* __restrict__ targ,
    const float* __restrict__ k2d, float* __restrict__ partial)
{
    __shared__ __align__(16) float smem[26 * 16 * 20];   // 8320 floats
    __shared__ float wsum[4];

    float* sP = smem;
    float* sT = smem + IN_ROWS * IN_STRIDE;

    const int tid = threadIdx.x;
    const int bid = blockIdx.x;
    const int img = bid >> 8;          // 256 tiles per image
    const int tin = bid & 255;
    const int ty  = tin >> 3;
    const int tx  = tin & 7;
    const int y0  = ty * TH;
    const int x0  = tx * TW;

    // exact 1D gaussian from the 2D kernel: k2d[5][j] = g5 * g[j], k2d[5][5] = g5^2
    float g[KS];
    {
        const float inv = rsqrtf(k2d[5 * KS + 5]);
        #pragma unroll
        for (int j = 0; j < KS; ++j) g[j] = k2d[5 * KS + j] * inv;
    }

    const float* __restrict__ Pimg = pred + (size_t)img * (IMG_H * IMG_W);
    const float* __restrict__ Timg = targ + (size_t)img * (IMG_H * IMG_W);

    // ---- stage 0: load halo tile (zero padding outside image) ----
    for (int i = tid; i < IN_ROWS * IN_COLS; i += 256) {   // 1924 elems
        const int r = i / IN_COLS;
        const int c = i - r * IN_COLS;
        const int gr = y0 - HALO + r;
        const int gc = x0 - HALO + c;
        float pv = 0.0f, tv = 0.0f;
        if ((unsigned)gr < IMG_H && (unsigned)gc < IMG_W) {
            const int o = gr * IMG_W + gc;
            pv = Pimg[o];
            tv = Timg[o];
        }
        sP[r * IN_STRIDE + c] = pv;
        sT[r * IN_STRIDE + c] = tv;
    }
    __syncthreads();

    // ---- stage 1: horizontal 11-tap pass, results held in registers ----
    // 26 rows x 16 col-groups (of 4) = 416 units; threads 0..159 do 2 units
    float res0[20], res1[20];
    const bool has1 = (tid + 256) < IN_ROWS * 16;

    auto do_unit = [&](int u, float* res) {
        const int r  = u >> 4;
        const int cg = u & 15;
        const float* rowP = sP + r * IN_STRIDE + cg * 4;
        const float* rowT = sT + r * IN_STRIDE + cg * 4;
        float p[16], t[16];
        #pragma unroll
        for (int q = 0; q < 4; ++q) {
            const float4 vp = *(const float4*)(rowP + 4 * q);
            const float4 vt = *(const float4*)(rowT + 4 * q);
            p[4*q+0] = vp.x; p[4*q+1] = vp.y; p[4*q+2] = vp.z; p[4*q+3] = vp.w;
            t[4*q+0] = vt.x; t[4*q+1] = vt.y; t[4*q+2] = vt.z; t[4*q+3] = vt.w;
        }
        // mu convs from raw p,t
        #pragma unroll
        for (int k = 0; k < 4; ++k) {
            float ax = 0.f, ay = 0.f;
            #pragma unroll
            for (int j = 0; j < KS; ++j) {
                ax = fmaf(g[j], p[k + j], ax);
                ay = fmaf(g[j], t[k + j], ay);
            }
            res[0 + k] = ax;
            res[4 + k] = ay;
        }
        // products once per pixel: pt new, squares in place
        float pt[16];
        #pragma unroll
        for (int i = 0; i < 16; ++i) {
            pt[i] = p[i] * t[i];
            p[i] *= p[i];
            t[i] *= t[i];
        }
        #pragma unroll
        for (int k = 0; k < 4; ++k) {
            float axx = 0.f, ayy = 0.f, axy = 0.f;
            #pragma unroll
            for (int j = 0; j < KS; ++j) {
                axx = fmaf(g[j], p [k + j], axx);
                ayy = fmaf(g[j], t [k + j], ayy);
                axy = fmaf(g[j], pt[k + j], axy);
            }
            res[ 8 + k] = axx;
            res[12 + k] = ayy;
            res[16 + k] = axy;
        }
    };

    do_unit(tid, res0);
    if (has1) do_unit(tid + 256, res1);
    __syncthreads();           // all reads of sP/sT complete

    // write packed h-maps into the SAME region (alias)
    {
        float4* dst = (float4*)(smem + tid * 20);        // 80 B aligned
        #pragma unroll
        for (int m = 0; m < 5; ++m)
            dst[m] = make_float4(res0[4*m], res0[4*m+1], res0[4*m+2], res0[4*m+3]);
        if (has1) {
            float4* dst1 = (float4*)(smem + (tid + 256) * 20);
            #pragma unroll
            for (int m = 0; m < 5; ++m)
                dst1[m] = make_float4(res1[4*m], res1[4*m+1], res1[4*m+2], res1[4*m+3]);
        }
    }
    __syncthreads();

    // ---- stage 2: vertical 11-tap pass + SSIM formula ----
    // thread -> (col, row-group of 4): 64 cols x 4 groups
    const int col = tid & 63;
    const int rg  = tid >> 6;
    const int cg  = col >> 2;
    const int ci  = col & 3;
    const float* Hb = smem + cg * 20 + ci;   // row step = 16*20 = 320 dwords

    float vx[14], vy[14], vxx[14], vyy[14], vxy[14];
    #pragma unroll
    for (int i = 0; i < 14; ++i) {
        const float* row = Hb + (rg * 4 + i) * 320;
        vx [i] = row[0];
        vy [i] = row[4];
        vxx[i] = row[8];
        vyy[i] = row[12];
        vxy[i] = row[16];
    }

    const float C1 = 1.0e-4f;   // (0.01*1)^2
    const float C2 = 9.0e-4f;   // (0.03*1)^2
    float lsum = 0.0f;
    #pragma unroll
    for (int k = 0; k < 4; ++k) {
        float mx = 0.f, my = 0.f, sxx = 0.f, syy = 0.f, sxy = 0.f;
        #pragma unroll
        for (int j = 0; j < KS; ++j) {
            mx  = fmaf(g[j], vx [k + j], mx);
            my  = fmaf(g[j], vy [k + j], my);
            sxx = fmaf(g[j], vxx[k + j], sxx);
            syy = fmaf(g[j], vyy[k + j], syy);
            sxy = fmaf(g[j], vxy[k + j], sxy);
        }
        const float mx2 = mx * mx;
        const float my2 = my * my;
        const float mxy = mx * my;
        const float num = (2.0f * mxy + C1) * (2.0f * (sxy - mxy) + C2);
        const float den = (mx2 + my2 + C1) * ((sxx - mx2) + (syy - my2) + C2);
        lsum += num / den;
    }

    // ---- block reduction ----
    #pragma unroll
    for (int off = 32; off > 0; off >>= 1)
        lsum += __shfl_down(lsum, off, 64);

    const int lane = tid & 63;
    const int wid  = tid >> 6;
    if (lane == 0) wsum[wid] = lsum;
    __syncthreads();
    if (tid == 0)
        partial[bid] = wsum[0] + wsum[1] + wsum[2] + wsum[3];
}

// ---------------- final reduction ----------------
__global__ __launch_bounds__(1024) void ssim_reduce_kernel(
    const float* __restrict__ partial, int n, float* __restrict__ out)
{
    const int tid = threadIdx.x;
    double s = 0.0;
    for (int i = tid; i < n; i += 1024) s += (double)partial[i];

    #pragma unroll
    for (int off = 32; off > 0; off >>= 1)
        s += __shfl_down(s, off, 64);

    __shared__ double dsum[16];
    const int lane = tid & 63;
    const int wid  = tid >> 6;
    if (lane == 0) dsum[wid] = s;
    __syncthreads();
    if (tid == 0) {
        double total = 0.0;
        #pragma unroll
        for (int w = 0; w < 16; ++w) total += dsum[w];
        out[0] = (float)(1.0 - total / TOTAL_N);
    }
}

extern "C" void kernel_launch(void* const* d_in, const int* in_sizes, int n_in,
                              void* d_out, int out_size, void* d_ws, size_t ws_size,
                              hipStream_t stream) {
    const float* pred = (const float*)d_in[0];
    const float* targ = (const float*)d_in[1];
    const float* k2d  = (const float*)d_in[2];
    float* out = (float*)d_out;
    float* ws  = (float*)d_ws;   // NBLOCKS partial sums

    ssim_tile_kernel<<<NBLOCKS, 256, 0, stream>>>(pred, targ, k2d, ws);
    ssim_reduce_kernel<<<1, 1024, 0, stream>>>(ws, NBLOCKS, out);
}

// Round 5
// 173.069 us; speedup vs baseline: 2.0073x; 2.0073x over previous
//
#include <hip/hip_runtime.h>
#include <math.h>

#define IMG_H 512
#define IMG_W 512
#define N_IMG 96            // 32 * 3
#define TW 64               // tile width (output cols)
#define TH 16               // tile height (output rows)
#define KS 11
#define IN_ROWS 26          // TH + 10
#define NUNITS (IN_ROWS * 16)   // 416 horizontal-conv units (4 px each)
#define PLANE 1690          // 26 * 65 (odd stride 65 -> conflict-free)
#define NBLOCKS (N_IMG * (IMG_W / TW) * (IMG_H / TH))   // 24576
#define TOTAL_N 25165824.0  // 32*3*512*512

// Design:
//  - NO input staging in LDS. Each stage-1 unit (row r, col-group cg) loads an
//    aligned 20-float window [x0+4cg-8, +20) for pred & targ straight from
//    global (5x b128 each, 16B-aligned). Halo overlap is served by L1/L2.
//  - Stage 1 computes 5 horizontal 11-tap maps (x, y, x^2, y^2, xy) for 4 px
//    and writes them to 5 LDS planes of row stride 65 (odd):
//      write banks  = (65r + 4cg + e) mod 32 = (r + 4cg + e) mod 32 -> 2-way (free)
//      read  banks  = (65row + col)   mod 32 = (row + col)  mod 32 -> 2-way (free)
//  - Nothing is held in registers across a barrier -> no spill pressure.
//  - LDS = 5*1690*4 = 33.8 KB -> 4 blocks/CU, 16 waves/CU.

__global__ __launch_bounds__(256, 4) void ssim_tile_kernel(
    const float* __restrict__ pred, const float* __restrict__ targ,
    const float* __restrict__ k2d, float* __restrict__ partial)
{
    __shared__ float H[5][PLANE];
    __shared__ float wsum[4];

    const int tid = threadIdx.x;
    const int bid = blockIdx.x;
    const int img = bid >> 8;          // 256 tiles per image
    const int tin = bid & 255;
    const int ty  = tin >> 3;
    const int tx  = tin & 7;
    const int y0  = ty * TH;
    const int x0  = tx * TW;

    // exact 1D gaussian from the 2D kernel: k2d[5][j] = g5 * g[j], k2d[5][5] = g5^2
    float g[KS];
    {
        const float inv = rsqrtf(k2d[5 * KS + 5]);
        #pragma unroll
        for (int j = 0; j < KS; ++j) g[j] = k2d[5 * KS + j] * inv;
    }

    const float* __restrict__ Pimg = pred + (size_t)img * (IMG_H * IMG_W);
    const float* __restrict__ Timg = targ + (size_t)img * (IMG_H * IMG_W);

    // ---- stage 1: horizontal 11-tap pass, global -> LDS planes ----
    #pragma unroll
    for (int b = 0; b < 2; ++b) {
        const int u = tid + (b << 8);
        if (u < NUNITS) {
            const int r    = u >> 4;
            const int cg   = u & 15;
            const int gr   = y0 - 5 + r;
            const int col0 = x0 + (cg << 2) - 8;   // 16B-aligned window start
            const bool rowok = ((unsigned)gr < (unsigned)IMG_H);
            const float* rowP = Pimg + (size_t)(rowok ? gr : 0) * IMG_W;
            const float* rowT = Timg + (size_t)(rowok ? gr : 0) * IMG_W;

            float p[20], t[20];
            if (rowok && col0 >= 0 && col0 + 20 <= IMG_W) {
                #pragma unroll
                for (int q = 0; q < 5; ++q) {
                    const float4 vp = *(const float4*)(rowP + col0 + 4 * q);
                    const float4 vt = *(const float4*)(rowT + col0 + 4 * q);
                    p[4*q+0] = vp.x; p[4*q+1] = vp.y; p[4*q+2] = vp.z; p[4*q+3] = vp.w;
                    t[4*q+0] = vt.x; t[4*q+1] = vt.y; t[4*q+2] = vt.z; t[4*q+3] = vt.w;
                }
            } else {
                #pragma unroll
                for (int e = 0; e < 20; ++e) {
                    const int c  = col0 + e;
                    const int cc = min(max(c, 0), IMG_W - 1);
                    const bool ok = rowok && (c >= 0) && (c < IMG_W);
                    const float pv = rowP[cc];
                    const float tv = rowT[cc];
                    p[e] = ok ? pv : 0.0f;
                    t[e] = ok ? tv : 0.0f;
                }
            }

            // mu convs (window offset 3: outputs use elems 3..17)
            float ax[4], ay[4];
            #pragma unroll
            for (int k = 0; k < 4; ++k) { ax[k] = 0.f; ay[k] = 0.f; }
            #pragma unroll
            for (int k = 0; k < 4; ++k) {
                #pragma unroll
                for (int j = 0; j < KS; ++j) {
                    ax[k] = fmaf(g[j], p[3 + k + j], ax[k]);
                    ay[k] = fmaf(g[j], t[3 + k + j], ay[k]);
                }
            }
            // products once per pixel (elems 3..17), squares in place
            float pt[15];
            #pragma unroll
            for (int i = 0; i < 15; ++i) {
                const float pv = p[3 + i];
                const float tv = t[3 + i];
                pt[i] = pv * tv;
                p[3 + i] = pv * pv;
                t[3 + i] = tv * tv;
            }
            float axx[4], ayy[4], axy[4];
            #pragma unroll
            for (int k = 0; k < 4; ++k) { axx[k] = 0.f; ayy[k] = 0.f; axy[k] = 0.f; }
            #pragma unroll
            for (int k = 0; k < 4; ++k) {
                #pragma unroll
                for (int j = 0; j < KS; ++j) {
                    axx[k] = fmaf(g[j], p[3 + k + j], axx[k]);
                    ayy[k] = fmaf(g[j], t[3 + k + j], ayy[k]);
                    axy[k] = fmaf(g[j], pt[k + j],    axy[k]);
                }
            }

            const int wb = r * 65 + (cg << 2);
            #pragma unroll
            for (int e = 0; e < 4; ++e) {
                H[0][wb + e] = ax[e];
                H[1][wb + e] = ay[e];
                H[2][wb + e] = axx[e];
                H[3][wb + e] = ayy[e];
                H[4][wb + e] = axy[e];
            }
        }
    }
    __syncthreads();

    // ---- stage 2: vertical 11-tap pass + SSIM formula ----
    const int col = tid & 63;
    const int rg  = tid >> 6;

    float vx[14], vy[14], vxx[14], vyy[14], vxy[14];
    #pragma unroll
    for (int i = 0; i < 14; ++i) {
        const int idx = (rg * 4 + i) * 65 + col;
        vx [i] = H[0][idx];
        vy [i] = H[1][idx];
        vxx[i] = H[2][idx];
        vyy[i] = H[3][idx];
        vxy[i] = H[4][idx];
    }

    const float C1 = 1.0e-4f;   // (0.01*1)^2
    const float C2 = 9.0e-4f;   // (0.03*1)^2
    float lsum = 0.0f;
    #pragma unroll
    for (int k = 0; k < 4; ++k) {
        float mx = 0.f, my = 0.f, sxx = 0.f, syy = 0.f, sxy = 0.f;
        #pragma unroll
        for (int j = 0; j < KS; ++j) {
            mx  = fmaf(g[j], vx [k + j], mx);
            my  = fmaf(g[j], vy [k + j], my);
            sxx = fmaf(g[j], vxx[k + j], sxx);
            syy = fmaf(g[j], vyy[k + j], syy);
            sxy = fmaf(g[j], vxy[k + j], sxy);
        }
        const float mx2 = mx * mx;
        const float my2 = my * my;
        const float mxy = mx * my;
        const float num = (2.0f * mxy + C1) * (2.0f * (sxy - mxy) + C2);
        const float den = (mx2 + my2 + C1) * ((sxx - mx2) + (syy - my2) + C2);
        lsum += num / den;
    }

    // ---- block reduction ----
    #pragma unroll
    for (int off = 32; off > 0; off >>= 1)
        lsum += __shfl_down(lsum, off, 64);

    const int lane = tid & 63;
    const int wid  = tid >> 6;
    if (lane == 0) wsum[wid] = lsum;
    __syncthreads();
    if (tid == 0)
        partial[bid] = wsum[0] + wsum[1] + wsum[2] + wsum[3];
}

// ---------------- final reduction ----------------
__global__ __launch_bounds__(1024) void ssim_reduce_kernel(
    const float* __restrict__ partial, int n, float* __restrict__ out)
{
    const int tid = threadIdx.x;
    double s = 0.0;
    for (int i = tid; i < n; i += 1024) s += (double)partial[i];

    #pragma unroll
    for (int off = 32; off > 0; off >>= 1)
        s += __shfl_down(s, off, 64);

    __shared__ double dsum[16];
    const int lane = tid & 63;
    const int wid  = tid >> 6;
    if (lane == 0) dsum[wid] = s;
    __syncthreads();
    if (tid == 0) {
        double total = 0.0;
        #pragma unroll
        for (int w = 0; w < 16; ++w) total += dsum[w];
        out[0] = (float)(1.0 - total / TOTAL_N);
    }
}

extern "C" void kernel_launch(void* const* d_in, const int* in_sizes, int n_in,
                              void* d_out, int out_size, void* d_ws, size_t ws_size,
                              hipStream_t stream) {
    const float* pred = (const float*)d_in[0];
    const float* targ = (const float*)d_in[1];
    const float* k2d  = (const float*)d_in[2];
    float* out = (float*)d_out;
    float* ws  = (float*)d_ws;   // NBLOCKS partial sums

    ssim_tile_kernel<<<NBLOCKS, 256, 0, stream>>>(pred, targ, k2d, ws);
    ssim_reduce_kernel<<<1, 1024, 0, stream>>>(ws, NBLOCKS, out);
}